// Round 8
// baseline (258.153 us; speedup 1.0000x reference)
//
#include <hip/hip_runtime.h>
#include <stdint.h>

// Q4_0 dequant-GEMM: y[t,o] = sum_k x[t,k] * s[o,k/32]*(q[o,k]-8) + bias[o]
// M=16 tokens, K=4096, N=11008. HBM floor ~29 us (180 MB qweight @6.3TB/s).
//
// History: R7 probe T_qgemm ~= 50 us marginal (incl. launch overhead);
// harness-fixed window ~= 205 us (688-MiB fills = workspace/output poison,
// unconditional). R4/R6/R8/R9 (sync convoy / barrier pipeline / counted
// vmcnt / coalesced staging + hoisted A): ALL NULL at 253-257 us =>
// qgemm internals are off the critical path at current margin.
//
// R10 = SINGLE DISPATCH. KSPLIT=1: 688 blocks x 256 thr -- entire grid
// co-resident (1024 slots @ 4 blk/CU >= 688), each block runs a 16-chunk
// K-pipeline over its full K=4096 and writes its 16x16 tile directly with
// bias. No partials, no workspace, no atomics, no memset, no reduce.
// Eliminates the 2nd dispatch's exec+gap+launch and 4x of the block
// prologues. Body = validated R9 contiguous/swizzled staging + R8 counted
// vmcnt(9) pipeline. If this is null too, every controllable term is
// falsified and the remaining window is harness-fixed => roofline.
// (R10 resubmit -- previous round failed on GPU acquisition, not the kernel.)

typedef __attribute__((ext_vector_type(8))) short bf16x8;  // 8 bf16 (4 VGPRs)
typedef __attribute__((ext_vector_type(4))) float f32x4;

#define OUT_F 11008
#define IN_F  4096
#define NB    128            // quant blocks along K
#define CHUNKS 16            // chunk-iterations per block (8 qblocks each)
#define NBLK  (OUT_F / 16)   // 688 blocks, one 16-row tile each, full K
#define M_TOK 16

__global__ __launch_bounds__(256, 4)
void qgemm_kernel(const float* __restrict__ x,
                  const int* __restrict__ qw,
                  const float* __restrict__ scales,
                  const float* __restrict__ bias,
                  float* __restrict__ out) {
  // Stage: [parity][wave][4 KB]. Per wave per chunk: 2 qblocks x 16 rows,
  // contiguous 256-B runs (R9): instr i lands rows 4i..4i+3, lane-linear.
  __shared__ uint4 stage[2][4][256];   // 32 KB
  __shared__ float red[4][256];        // 4 KB

  const int ob   = blockIdx.x << 4;        // 16 output features per tile
  const int tid  = threadIdx.x;
  const int wave = tid >> 6;
  const int lane = tid & 63;
  const int col  = lane & 15;              // readback: token (A) / out row (B)
  const int kr   = lane >> 4;              // readback: k sub-chunk 0..3
  const int rg   = lane >> 4;              // staging: row-in-group 0..3
  // staging source slot, XOR-swizzled within the 256-B row window
  const int slot_g = (lane & 15) ^ (2 * rg);

  // Contiguous staging: instr i covers rows ob+4i+rg, byte slot_g*16 of the
  // wave's 2-qblock (256 B) window. LDS dest lane-linear (16 B/lane), so
  // LDS[i*1024 + rg*256 + s*16] holds global slot s ^ (2*rg).  (validated R9)
  auto STAGE = [&](int parity, int t) {
    const int kb0 = t * 8 + wave * 2;
#pragma unroll
    for (int i = 0; i < 4; ++i) {
      const char* src = (const char*)qw
          + (size_t)(ob + 4 * i + rg) * (IN_F * 4)
          + (size_t)kb0 * 128 + slot_g * 16;
      __builtin_amdgcn_global_load_lds(
          (const __attribute__((address_space(1))) void*)src,
          (__attribute__((address_space(3))) void*)(&stage[parity][wave][i * 64]),
          16, 0, 0);
    }
  };

  f32x4  xv[2][2][2];   // [parity][qblock][half] registers (static-indexed)
  float2 scb[2];        // [parity] per-wave scale pair
  const float* xbase = x + col * IN_F + kr * 8;
  const float* sbase = scales + (ob + col) * NB;
  // Prefetch x (L2-hot) + scales for chunk t: 4x dwordx4 + 1x dwordx2.
  auto PREF = [&](int parity, int t) {
    const int kb0 = t * 8 + wave * 2;
#pragma unroll
    for (int q = 0; q < 2; ++q) {
      const float* xp = xbase + (size_t)(kb0 + q) * 32;
      xv[parity][q][0] = *(const f32x4*)xp;
      xv[parity][q][1] = *(const f32x4*)(xp + 4);
    }
    scb[parity] = *(const float2*)(sbase + kb0);
  };

  // Readback LDS index (uint4 units): row col lives in instr col>>2,
  // row-group col&3; qblock q slot (q*8 + 2*kr), un-swizzled by ^2*(col&3).
  const int rb_base = (col >> 2) * 64 + (col & 3) * 16;
  const int rb_x    = 2 * (col & 3);

  f32x4 acc = {0.f, 0.f, 0.f, 0.f};

  // Prologue: issue chunk 0 (9 VMEM ops); iter 0's counted wait covers it.
  STAGE(0, 0);
  PREF(0, 0);
  __builtin_amdgcn_sched_barrier(0);   // pin: chunk0 loads issue first

#pragma unroll
  for (int t = 0; t < CHUNKS; ++t) {
    const int nb = t & 1;
    if (t + 1 < CHUNKS) {      // issue next chunk: stays in flight past wait
      STAGE(nb ^ 1, t + 1);
      PREF(nb ^ 1, t + 1);
    }
    __builtin_amdgcn_sched_barrier(0); // pin issue order (vmcnt is in-order)
    // Counted wait: 9 newest (chunk t+1) may remain in flight; chunk t's
    // 4 global_load_lds + 5 reg-loads are complete. Last iter: drain.
    if (t + 1 < CHUNKS) {
      asm volatile("s_waitcnt vmcnt(9)" ::: "memory");
    } else {
      asm volatile("s_waitcnt vmcnt(0)" ::: "memory");
    }
    __builtin_amdgcn_sched_barrier(0); // rule #18: keep ds_read below the wait
#pragma unroll
    for (int q = 0; q < 2; ++q) {
      const int idx0 = rb_base + ((q * 8 + 2 * kr) ^ rb_x);
      uint4 q0 = stage[nb][wave][idx0];      // bytes kr*32 .. +16 of qblock
      uint4 q1 = stage[nb][wave][idx0 + 1];  // bytes kr*32+16 .. +32
      float sc  = (q == 0) ? scb[nb].x : scb[nb].y;
      float m8s = -8.f * sc;
      union { uint32_t u[4]; bf16x8 v; } A, B;
      // pack x -> bf16 (round-half-up) via v_perm
      uint32_t a0 = __float_as_uint(xv[nb][q][0].x) + 0x8000u;
      uint32_t a1 = __float_as_uint(xv[nb][q][0].y) + 0x8000u;
      uint32_t a2 = __float_as_uint(xv[nb][q][0].z) + 0x8000u;
      uint32_t a3 = __float_as_uint(xv[nb][q][0].w) + 0x8000u;
      uint32_t a4 = __float_as_uint(xv[nb][q][1].x) + 0x8000u;
      uint32_t a5 = __float_as_uint(xv[nb][q][1].y) + 0x8000u;
      uint32_t a6 = __float_as_uint(xv[nb][q][1].z) + 0x8000u;
      uint32_t a7 = __float_as_uint(xv[nb][q][1].w) + 0x8000u;
      A.u[0] = __builtin_amdgcn_perm(a1, a0, 0x07060302u);
      A.u[1] = __builtin_amdgcn_perm(a3, a2, 0x07060302u);
      A.u[2] = __builtin_amdgcn_perm(a5, a4, 0x07060302u);
      A.u[3] = __builtin_amdgcn_perm(a7, a6, 0x07060302u);
      // dequant: w = s*q - 8s (exact in fp32), truncate-pack to bf16
      uint32_t w0 = __float_as_uint(fmaf((float)(int)q0.x, sc, m8s));
      uint32_t w1 = __float_as_uint(fmaf((float)(int)q0.y, sc, m8s));
      uint32_t w2 = __float_as_uint(fmaf((float)(int)q0.z, sc, m8s));
      uint32_t w3 = __float_as_uint(fmaf((float)(int)q0.w, sc, m8s));
      uint32_t w4 = __float_as_uint(fmaf((float)(int)q1.x, sc, m8s));
      uint32_t w5 = __float_as_uint(fmaf((float)(int)q1.y, sc, m8s));
      uint32_t w6 = __float_as_uint(fmaf((float)(int)q1.z, sc, m8s));
      uint32_t w7 = __float_as_uint(fmaf((float)(int)q1.w, sc, m8s));
      B.u[0] = __builtin_amdgcn_perm(w1, w0, 0x07060302u);
      B.u[1] = __builtin_amdgcn_perm(w3, w2, 0x07060302u);
      B.u[2] = __builtin_amdgcn_perm(w5, w4, 0x07060302u);
      B.u[3] = __builtin_amdgcn_perm(w7, w6, 0x07060302u);
      acc = __builtin_amdgcn_mfma_f32_16x16x32_bf16(A.v, B.v, acc, 0, 0, 0);
    }
    // no barrier: stage buffers are wave-private; the counted wait is the
    // only synchronization needed in the K-loop.
  }

  // Cross-wave K-combine. C/D layout: lane holds D[row=kr*4+r][col]
  // (row = token, col = output feature).
#pragma unroll
  for (int r = 0; r < 4; ++r)
    red[wave][(kr * 4 + r) * 16 + col] = acc[r];
  __syncthreads();   // the one cross-wave sync in the kernel

  float v = red[0][tid] + red[1][tid] + red[2][tid] + red[3][tid];
  const int t = tid >> 4;            // token
  const int o = ob + (tid & 15);     // output feature
  out[(size_t)t * OUT_F + o] = v + bias[o];   // write-once, final
}

// ---------------------------------------------------------------------------
extern "C" void kernel_launch(void* const* d_in, const int* in_sizes, int n_in,
                              void* d_out, int out_size, void* d_ws, size_t ws_size,
                              hipStream_t stream) {
  const float* x      = (const float*)d_in[0];
  const int*   qw     = (const int*)d_in[1];
  const float* scales = (const float*)d_in[2];
  const float* bias   = (const float*)d_in[3];
  float* out = (float*)d_out;
  (void)d_ws; (void)ws_size;

  // Single dispatch: full-K tiles, direct final store (bias fused).
  qgemm_kernel<<<NBLK, 256, 0, stream>>>(x, qw, scales, bias, out);
}